// Round 1
// baseline (4044.716 us; speedup 1.0000x reference)
//
#include <hip/hip_runtime.h>

typedef _Float16 f16;
typedef _Float16 f16x2 __attribute__((ext_vector_type(2)));
typedef _Float16 f16x8 __attribute__((ext_vector_type(8)));
typedef float f32x4 __attribute__((ext_vector_type(4)));

#define NB 256
#define NT 1024
#define ND 256
#define NU 128
#define NSIG 20
#define N3U 384
#define BT (NB * NT)

static __device__ __forceinline__ float sigmoid_fast(float x) {
    // 1/(1+exp(-x)); graceful at +-inf
    return __builtin_amdgcn_rcpf(1.f + __expf(-x));
}
static __device__ __forceinline__ float tanh_fast(float x) {
    // 1 - 2/(exp(2x)+1); exp overflow -> +1, underflow -> -1
    return 1.f - 2.f * __builtin_amdgcn_rcpf(__expf(2.f * x) + 1.f);
}

// ---------------------------------------------------------------------------
// Kernel 1: x_proj = inputs @ input_kernel   [BT,256] @ [256,384] -> f16 [BT,384]
// 64x64 tile, 256 threads (4 waves), mfma_f32_16x16x32_f16, K-loop of 8.
// ---------------------------------------------------------------------------
__global__ __launch_bounds__(256) void xproj_gemm(
    const float* __restrict__ A,   // [BT, 256]
    const float* __restrict__ Wk,  // [256, 384]
    f16* __restrict__ out)         // [BT, 384]
{
    const int n0 = blockIdx.x * 64;   // 0..5  -> col tile
    const int m0 = blockIdx.y * 64;   // 0..4095 -> row tile
    const int tid = threadIdx.x;
    const int lane = tid & 63;
    const int w = tid >> 6;           // wave 0..3, owns rows 16w..16w+15
    const int mm = lane & 15;
    const int q = lane >> 4;          // 0..3

    // padded stride 40 f16 (80 B) -> 2-way bank aliasing only (free)
    __shared__ __align__(16) f16 sA[64 * 40];   // [row][k]
    __shared__ __align__(16) f16 sB[64 * 40];   // transposed: [n][k]

    f32x4 acc[4] = {{0.f,0.f,0.f,0.f},{0.f,0.f,0.f,0.f},{0.f,0.f,0.f,0.f},{0.f,0.f,0.f,0.f}};

    // A staging map: thread -> (row, 8-wide k chunk)
    const int ar = tid >> 2;            // 0..63
    const int ac = (tid & 3) * 8;       // 0,8,16,24
    // B staging map: thread -> (col n, 8-wide k chunk); global loads coalesced per k-row
    const int bn = tid & 63;            // 0..63
    const int bkc = (tid >> 6) * 8;     // 0,8,16,24

    for (int kt = 0; kt < ND; kt += 32) {
        // ---- stage A tile [64 x 32] fp32 -> f16
        const float4 a0 = *(const float4*)(A + (size_t)(m0 + ar) * ND + kt + ac);
        const float4 a1 = *(const float4*)(A + (size_t)(m0 + ar) * ND + kt + ac + 4);
        f16x8 av;
        av[0]=(f16)a0.x; av[1]=(f16)a0.y; av[2]=(f16)a0.z; av[3]=(f16)a0.w;
        av[4]=(f16)a1.x; av[5]=(f16)a1.y; av[6]=(f16)a1.z; av[7]=(f16)a1.w;
        *(f16x8*)(sA + ar * 40 + ac) = av;

        // ---- stage B tile [32 x 64] fp32 -> f16, transposed to [n][k]
        f16x8 bv;
        #pragma unroll
        for (int i = 0; i < 8; ++i)
            bv[i] = (f16)Wk[(size_t)(kt + bkc + i) * N3U + n0 + bn];
        *(f16x8*)(sB + bn * 40 + bkc) = bv;

        __syncthreads();

        // ---- fragments + MFMA
        // A-frag: A[m = lane&15][k = q*8 + j]
        f16x8 afrag = *(const f16x8*)(sA + (w * 16 + mm) * 40 + q * 8);
        #pragma unroll
        for (int nt = 0; nt < 4; ++nt) {
            // B-frag: B[k = q*8 + j][n = lane&15]  (sB is [n][k])
            f16x8 bfrag = *(const f16x8*)(sB + (nt * 16 + mm) * 40 + q * 8);
            acc[nt] = __builtin_amdgcn_mfma_f32_16x16x32_f16(afrag, bfrag, acc[nt], 0, 0, 0);
        }
        __syncthreads();
    }

    // ---- epilogue: D[row=(lane>>4)*4+r][col=lane&15]
    #pragma unroll
    for (int nt = 0; nt < 4; ++nt) {
        #pragma unroll
        for (int r = 0; r < 4; ++r) {
            const int row = m0 + w * 16 + q * 4 + r;
            const int col = n0 + nt * 16 + mm;
            out[(size_t)row * N3U + col] = (f16)acc[nt][r];
        }
    }
}

// ---------------------------------------------------------------------------
// Kernel 2: f = sigmoid(signatures @ forget_kernel + b_f) -> f16 [BT,128]
// ---------------------------------------------------------------------------
__global__ __launch_bounds__(256) void fgate_kernel(
    const float* __restrict__ sig,   // [BT, 20]
    const float* __restrict__ Wf,    // [20, 128]
    const float* __restrict__ bias,  // [512]
    f16* __restrict__ fout)          // [BT, 128]
{
    const int gid = blockIdx.x * 256 + threadIdx.x;
    const int u = gid & 127;
    const int bt = gid >> 7;
    float acc = bias[NU + u];        // b_f
    #pragma unroll
    for (int s = 0; s < NSIG; ++s)
        acc += sig[(size_t)bt * NSIG + s] * Wf[s * NU + u];
    fout[gid] = (f16)sigmoid_fast(acc);
}

// ---------------------------------------------------------------------------
// Kernel 3: the recurrence. One block per batch row, 384 threads (6 waves).
// Thread j owns gate column j; W_r[:,j] lives in VGPRs as 64 packed f16x2.
// h broadcast via LDS; v_dot2_f32_f16 inner product; 2 barriers/step.
// ---------------------------------------------------------------------------
__global__ __launch_bounds__(384) void recur_kernel(
    const f16* __restrict__ xp,      // [BT, 384]
    const f16* __restrict__ fg,      // [BT, 128]
    const float* __restrict__ Wr,    // [128, 384]
    const float* __restrict__ bias,  // [512]
    float* __restrict__ out)         // [BT, 128]
{
    const int b = blockIdx.x;
    const int j = threadIdx.x;

    __shared__ __align__(16) f16 h_sh[NU];
    __shared__ float gate_sh[N3U];

    // preload W_r column j (coalesced across threads), packed f16 pairs
    f16x2 wr[64];
    #pragma unroll 16
    for (int k2 = 0; k2 < 64; ++k2) {
        const float w0 = Wr[(size_t)(2 * k2) * N3U + j];
        const float w1 = Wr[(size_t)(2 * k2 + 1) * N3U + j];
        f16x2 p; p[0] = (f16)w0; p[1] = (f16)w1;
        wr[k2] = p;
    }

    float bi = 0.f, bc = 0.f, bo = 0.f, cstate = 0.f;
    if (j < NU) {
        bi = bias[j];
        bc = bias[2 * NU + j];
        bo = bias[3 * NU + j];
        h_sh[j] = (f16)0.f;
    }
    __syncthreads();

    const size_t base_x = (size_t)b * NT * N3U + j;
    const size_t base_u = (size_t)b * NT * NU + (j < NU ? j : 0);

    float x_cur = (float)xp[base_x];
    float f_cur = (j < NU) ? (float)fg[base_u] : 0.f;

    for (int t = 0; t < NT; ++t) {
        // prefetch next step's x / f (no dependence on h -> hides latency)
        const int tn = (t + 1 < NT) ? t + 1 : t;
        const float x_nxt = (float)xp[base_x + (size_t)tn * N3U];
        float f_nxt = 0.f;
        if (j < NU) f_nxt = (float)fg[base_u + (size_t)tn * NU];

        // gate_j = x_j + sum_k h[k] * Wr[k][j]   (4 independent chains)
        float g0 = x_cur, g1 = 0.f, g2 = 0.f, g3 = 0.f;
        const uint4* h4 = (const uint4*)h_sh;
        #pragma unroll
        for (int kk = 0; kk < 16; ++kk) {
            const uint4 hv = h4[kk];   // broadcast read, 8 f16
            g0 = __builtin_amdgcn_fdot2(__builtin_bit_cast(f16x2, hv.x), wr[kk * 4 + 0], g0, false);
            g1 = __builtin_amdgcn_fdot2(__builtin_bit_cast(f16x2, hv.y), wr[kk * 4 + 1], g1, false);
            g2 = __builtin_amdgcn_fdot2(__builtin_bit_cast(f16x2, hv.z), wr[kk * 4 + 2], g2, false);
            g3 = __builtin_amdgcn_fdot2(__builtin_bit_cast(f16x2, hv.w), wr[kk * 4 + 3], g3, false);
        }
        gate_sh[j] = (g0 + g1) + (g2 + g3);
        __syncthreads();   // gates ready; all h_sh reads done

        if (j < NU) {
            const float gi = gate_sh[j] + bi;
            const float gc = gate_sh[j + NU] + bc;
            const float go = gate_sh[j + 2 * NU] + bo;
            const float it = sigmoid_fast(gi);
            const float ch = tanh_fast(gc);
            const float ot = sigmoid_fast(go);
            cstate = f_cur * cstate + it * ch;
            const float h = ot * tanh_fast(cstate);
            out[base_u + (size_t)t * NU] = h;
            h_sh[j] = (f16)h;
        }
        __syncthreads();   // h_sh updated for next step

        x_cur = x_nxt;
        f_cur = f_nxt;
    }
}

// ---------------------------------------------------------------------------
extern "C" void kernel_launch(void* const* d_in, const int* in_sizes, int n_in,
                              void* d_out, int out_size, void* d_ws, size_t ws_size,
                              hipStream_t stream) {
    const float* inputs = (const float*)d_in[0];   // [256,1024,256]
    const float* sig    = (const float*)d_in[1];   // [256,1024,20]
    const float* Wk     = (const float*)d_in[2];   // [256,384]
    const float* Wr     = (const float*)d_in[3];   // [128,384]
    const float* Wf     = (const float*)d_in[4];   // [20,128]
    const float* bias   = (const float*)d_in[5];   // [512]
    float* out = (float*)d_out;                    // [256,1024,128]

    f16* xp = (f16*)d_ws;                                        // 192 MiB
    f16* fg = (f16*)((char*)d_ws + (size_t)BT * N3U * sizeof(f16)); // +64 MiB

    xproj_gemm<<<dim3(N3U / 64, BT / 64), 256, 0, stream>>>(inputs, Wk, xp);
    fgate_kernel<<<dim3((BT * NU) / 256), 256, 0, stream>>>(sig, Wf, bias, fg);
    recur_kernel<<<dim3(NB), 384, 0, stream>>>(xp, fg, Wr, bias, out);

    (void)in_sizes; (void)n_in; (void)out_size; (void)ws_size;
}

// Round 2
// 1339.733 us; speedup vs baseline: 3.0190x; 3.0190x over previous
//
#include <hip/hip_runtime.h>

typedef _Float16 f16;
typedef _Float16 f16x2 __attribute__((ext_vector_type(2)));
typedef _Float16 f16x8 __attribute__((ext_vector_type(8)));
typedef float f32x4 __attribute__((ext_vector_type(4)));

#define NB 256
#define NT 1024
#define ND 256
#define NU 128
#define NSIG 20
#define N3U 384
#define BT (NB * NT)
#define CH 16              // timesteps per LDS chunk
#define NCHUNK (NT / CH)

static __device__ __forceinline__ float sigmoid_fast(float x) {
    return __builtin_amdgcn_rcpf(1.f + __expf(-x));
}
static __device__ __forceinline__ float tanh_fast(float x) {
    return 1.f - 2.f * __builtin_amdgcn_rcpf(__expf(2.f * x) + 1.f);
}

// ---------------------------------------------------------------------------
// Kernel 1: x_proj = inputs @ input_kernel   [BT,256] @ [256,384] -> f16 [BT,384]
// (unchanged from R0 — to be tuned after the recurrence is fixed)
// ---------------------------------------------------------------------------
__global__ __launch_bounds__(256) void xproj_gemm(
    const float* __restrict__ A,   // [BT, 256]
    const float* __restrict__ Wk,  // [256, 384]
    f16* __restrict__ out)         // [BT, 384]
{
    const int n0 = blockIdx.x * 64;
    const int m0 = blockIdx.y * 64;
    const int tid = threadIdx.x;
    const int lane = tid & 63;
    const int w = tid >> 6;
    const int mm = lane & 15;
    const int q = lane >> 4;

    __shared__ __align__(16) f16 sA[64 * 40];
    __shared__ __align__(16) f16 sB[64 * 40];

    f32x4 acc[4] = {{0.f,0.f,0.f,0.f},{0.f,0.f,0.f,0.f},{0.f,0.f,0.f,0.f},{0.f,0.f,0.f,0.f}};

    const int ar = tid >> 2;
    const int ac = (tid & 3) * 8;
    const int bn = tid & 63;
    const int bkc = (tid >> 6) * 8;

    for (int kt = 0; kt < ND; kt += 32) {
        const float4 a0 = *(const float4*)(A + (size_t)(m0 + ar) * ND + kt + ac);
        const float4 a1 = *(const float4*)(A + (size_t)(m0 + ar) * ND + kt + ac + 4);
        f16x8 av;
        av[0]=(f16)a0.x; av[1]=(f16)a0.y; av[2]=(f16)a0.z; av[3]=(f16)a0.w;
        av[4]=(f16)a1.x; av[5]=(f16)a1.y; av[6]=(f16)a1.z; av[7]=(f16)a1.w;
        *(f16x8*)(sA + ar * 40 + ac) = av;

        f16x8 bv;
        #pragma unroll
        for (int i = 0; i < 8; ++i)
            bv[i] = (f16)Wk[(size_t)(kt + bkc + i) * N3U + n0 + bn];
        *(f16x8*)(sB + bn * 40 + bkc) = bv;

        __syncthreads();

        f16x8 afrag = *(const f16x8*)(sA + (w * 16 + mm) * 40 + q * 8);
        #pragma unroll
        for (int nt = 0; nt < 4; ++nt) {
            f16x8 bfrag = *(const f16x8*)(sB + (nt * 16 + mm) * 40 + q * 8);
            acc[nt] = __builtin_amdgcn_mfma_f32_16x16x32_f16(afrag, bfrag, acc[nt], 0, 0, 0);
        }
        __syncthreads();
    }

    #pragma unroll
    for (int nt = 0; nt < 4; ++nt) {
        #pragma unroll
        for (int r = 0; r < 4; ++r) {
            const int row = m0 + w * 16 + q * 4 + r;
            const int col = n0 + nt * 16 + mm;
            out[(size_t)row * N3U + col] = (f16)acc[nt][r];
        }
    }
}

// ---------------------------------------------------------------------------
// Kernel 2: f = sigmoid(signatures @ forget_kernel + b_f) -> f16 [BT,128]
// ---------------------------------------------------------------------------
__global__ __launch_bounds__(256) void fgate_kernel(
    const float* __restrict__ sig,
    const float* __restrict__ Wf,
    const float* __restrict__ bias,
    f16* __restrict__ fout)
{
    const int gid = blockIdx.x * 256 + threadIdx.x;
    const int u = gid & 127;
    const int bt = gid >> 7;
    float acc = bias[NU + u];
    #pragma unroll
    for (int s = 0; s < NSIG; ++s)
        acc += sig[(size_t)bt * NSIG + s] * Wf[s * NU + u];
    fout[gid] = (f16)sigmoid_fast(acc);
}

// ---------------------------------------------------------------------------
// Kernel 3: recurrence. One block per batch row, 384 threads (6 waves).
// __launch_bounds__(384,2): VGPR cap 256 so wr[64] STAYS IN REGISTERS
// (R0 compiled at 52 VGPRs -> wr spilled to scratch -> ~7900 cyc/step).
// x/f staged per 16-step chunk into double-buffered LDS; out buffered in LDS,
// flushed per chunk -> per-step barriers drain no global traffic.
// ---------------------------------------------------------------------------
__global__ __launch_bounds__(384, 2) void recur_kernel(
    const f16* __restrict__ xp,      // [BT, 384]
    const f16* __restrict__ fg,      // [BT, 128]
    const float* __restrict__ Wr,    // [128, 384]
    const float* __restrict__ bias,  // [512]
    float* __restrict__ out)         // [BT, 128]
{
    const int b = blockIdx.x;
    const int j = threadIdx.x;

    __shared__ __align__(16) f16 x_sh[2][CH * N3U];   // 2 x 12 KB
    __shared__ __align__(16) f16 f_sh[2][CH * NU];    // 2 x 4 KB
    __shared__ __align__(16) float o_sh[CH * NU];     // 8 KB
    __shared__ __align__(16) f16 h_sh[2][NU];         // double-buffered h
    __shared__ __align__(16) float gate_sh[N3U];

    // ---- preload W_r column j into VGPRs as 64 packed f16x2 (fully unrolled)
    f16x2 wr[64];
    #pragma unroll
    for (int k2 = 0; k2 < 64; ++k2) {
        const float w0 = Wr[(size_t)(2 * k2) * N3U + j];
        const float w1 = Wr[(size_t)(2 * k2 + 1) * N3U + j];
        f16x2 p; p[0] = (f16)w0; p[1] = (f16)w1;
        wr[k2] = p;
    }

    float bi = 0.f, bc = 0.f, bo = 0.f, cstate = 0.f;
    if (j < NU) {
        bi = bias[j];
        bc = bias[2 * NU + j];
        bo = bias[3 * NU + j];
        h_sh[0][j] = (f16)0.f;
    }

    // ---- stage chunk 0 into buffer 0
    {
        const uint4* xsrc = (const uint4*)(xp + ((size_t)b * NT) * N3U);
        uint4* xdst = (uint4*)x_sh[0];
        xdst[j] = xsrc[j];
        xdst[j + 384] = xsrc[j + 384];
        if (j < 256) {
            const uint4* fsrc = (const uint4*)(fg + ((size_t)b * NT) * NU);
            ((uint4*)f_sh[0])[j] = fsrc[j];
        }
    }
    __syncthreads();

    int p = 0;   // h_sh buffer in use
    for (int c = 0; c < NCHUNK; ++c) {
        const int bb = c & 1;

        // issue next chunk's global loads NOW (held in regs until chunk end)
        uint4 xs0, xs1, fs0;
        const bool have_next = (c + 1 < NCHUNK);
        if (have_next) {
            const uint4* xsrc = (const uint4*)(xp + ((size_t)b * NT + (size_t)(c + 1) * CH) * N3U);
            xs0 = xsrc[j];
            xs1 = xsrc[j + 384];
            if (j < 256) {
                const uint4* fsrc = (const uint4*)(fg + ((size_t)b * NT + (size_t)(c + 1) * CH) * NU);
                fs0 = fsrc[j];
            }
        }

        for (int t = 0; t < CH; ++t) {
            // gate_j = x_j + sum_k h[k] * Wr[k][j]   (4 independent chains)
            float g0 = (float)x_sh[bb][t * N3U + j], g1 = 0.f, g2 = 0.f, g3 = 0.f;
            const uint4* h4 = (const uint4*)h_sh[p];
            #pragma unroll
            for (int kk = 0; kk < 16; ++kk) {
                const uint4 hv = h4[kk];   // wave-uniform address -> broadcast
                g0 = __builtin_amdgcn_fdot2(__builtin_bit_cast(f16x2, hv.x), wr[kk * 4 + 0], g0, false);
                g1 = __builtin_amdgcn_fdot2(__builtin_bit_cast(f16x2, hv.y), wr[kk * 4 + 1], g1, false);
                g2 = __builtin_amdgcn_fdot2(__builtin_bit_cast(f16x2, hv.z), wr[kk * 4 + 2], g2, false);
                g3 = __builtin_amdgcn_fdot2(__builtin_bit_cast(f16x2, hv.w), wr[kk * 4 + 3], g3, false);
            }
            gate_sh[j] = (g0 + g1) + (g2 + g3);
            __syncthreads();   // gates ready (lgkm-only drain: no global ops pending*)

            if (j < NU) {
                const float gi = gate_sh[j] + bi;
                const float gc = gate_sh[j + NU] + bc;
                const float go = gate_sh[j + 2 * NU] + bo;
                const float it = sigmoid_fast(gi);
                const float chv = tanh_fast(gc);
                const float ot = sigmoid_fast(go);
                const float ft = (float)f_sh[bb][t * NU + j];
                cstate = ft * cstate + it * chv;
                const float h = ot * tanh_fast(cstate);
                o_sh[t * NU + j] = h;
                h_sh[p ^ 1][j] = (f16)h;   // write OTHER buffer: no read race
            }
            __syncthreads();
            p ^= 1;
        }

        // ---- flush out chunk (8 KB contiguous, coalesced)
        {
            uint4* dst = (uint4*)(out + ((size_t)b * NT + (size_t)c * CH) * NU);
            const uint4* src = (const uint4*)o_sh;
            if (j < 256) {
                dst[j] = src[j];
                dst[j + 256] = src[j + 256];
            }
        }

        // ---- commit prefetched chunk to the other LDS buffer
        if (have_next) {
            uint4* xdst = (uint4*)x_sh[bb ^ 1];
            xdst[j] = xs0;
            xdst[j + 384] = xs1;
            if (j < 256) ((uint4*)f_sh[bb ^ 1])[j] = fs0;
        }
        __syncthreads();   // chunk barrier: staging visible, o_sh reads drained
    }
}

// ---------------------------------------------------------------------------
extern "C" void kernel_launch(void* const* d_in, const int* in_sizes, int n_in,
                              void* d_out, int out_size, void* d_ws, size_t ws_size,
                              hipStream_t stream) {
    const float* inputs = (const float*)d_in[0];   // [256,1024,256]
    const float* sig    = (const float*)d_in[1];   // [256,1024,20]
    const float* Wk     = (const float*)d_in[2];   // [256,384]
    const float* Wr     = (const float*)d_in[3];   // [128,384]
    const float* Wf     = (const float*)d_in[4];   // [20,128]
    const float* bias   = (const float*)d_in[5];   // [512]
    float* out = (float*)d_out;                    // [256,1024,128]

    f16* xp = (f16*)d_ws;
    f16* fg = (f16*)((char*)d_ws + (size_t)BT * N3U * sizeof(f16));

    xproj_gemm<<<dim3(N3U / 64, BT / 64), 256, 0, stream>>>(inputs, Wk, xp);
    fgate_kernel<<<dim3((BT * NU) / 256), 256, 0, stream>>>(sig, Wf, bias, fg);
    recur_kernel<<<dim3(NB), 384, 0, stream>>>(xp, fg, Wr, bias, out);

    (void)in_sizes; (void)n_in; (void)out_size; (void)ws_size;
}